// Round 8
// baseline (14094.931 us; speedup 1.0000x reference)
//
#include <hip/hip_runtime.h>
#include <stdint.h>

#define SEQ  2048
#define HID  2048
#define INP  1024
#define OUTW 512
#define SENT 0x7F7F7F7Fu   // 3.39e38f; |h|<1 so a real h word never matches

__device__ __forceinline__ unsigned short f2bf(float x){
  unsigned int u = __float_as_uint(x);
  u += 0x7fffu + ((u >> 16) & 1u);           // RNE
  return (unsigned short)(u >> 16);
}
__device__ __forceinline__ float bf_lo(unsigned int w){ return __uint_as_float(w << 16); }
__device__ __forceinline__ float bf_hi(unsigned int w){ return __uint_as_float(w & 0xffff0000u); }

// ---------------- Phase 0: sentinel-fill hist ----------------
__global__ __launch_bounds__(256)
void fill_hist(uint4* __restrict__ hist4){
  size_t i = (size_t)blockIdx.x*blockDim.x + threadIdx.x;   // 1,048,576 uint4 = 16 MB
  hist4[i] = make_uint4(SENT,SENT,SENT,SENT);
}

// ---------------- Phase A: Xproj[b][t][u][g] = W_g[j][2048:] @ x_t + b_g[j], bf16 ----------------
__global__ __launch_bounds__(256)
void xproj_gemm(const float* __restrict__ Wf, const float* __restrict__ Wi,
                const float* __restrict__ Wc, const float* __restrict__ Wo,
                const float* __restrict__ bfv, const float* __restrict__ biv,
                const float* __restrict__ bcv, const float* __restrict__ bov,
                const float* __restrict__ X, unsigned short* __restrict__ xproj)
{
  __shared__ float As[16][68];
  __shared__ float Bs[16][68];
  const int t0 = blockIdx.x * 64;
  const int r0 = blockIdx.y * 64;
  const int gate = r0 >> 11;
  const int j0 = r0 & 2047;
  const float* Wg = gate==0?Wf:gate==1?Wi:gate==2?Wc:Wo;
  const float* bg = gate==0?bfv:gate==1?biv:gate==2?bcv:bov;
  const int tid = threadIdx.x;
  const int tx = tid & 15, ty = tid >> 4;
  const int lr = tid >> 2;
  const int lk = (tid & 3) * 4;
  float acc[4][4] = {};
  for (int k0 = 0; k0 < INP; k0 += 16){
    float4 av = *(const float4*)(Wg + (size_t)(j0+lr)*3072 + 2048 + k0 + lk);
    float4 bv = *(const float4*)(X  + (size_t)(t0+lr)*INP  + k0 + lk);
    __syncthreads();
    As[lk+0][lr]=av.x; As[lk+1][lr]=av.y; As[lk+2][lr]=av.z; As[lk+3][lr]=av.w;
    Bs[lk+0][lr]=bv.x; Bs[lk+1][lr]=bv.y; Bs[lk+2][lr]=bv.z; Bs[lk+3][lr]=bv.w;
    __syncthreads();
    #pragma unroll
    for (int kk=0;kk<16;kk++){
      float a[4], bb[4];
      #pragma unroll
      for (int i=0;i<4;i++) a[i]  = As[kk][ty*4+i];
      #pragma unroll
      for (int j=0;j<4;j++) bb[j] = Bs[kk][tx*4+j];
      #pragma unroll
      for (int i=0;i<4;i++)
        #pragma unroll
        for (int j=0;j<4;j++)
          acc[i][j] = fmaf(a[i], bb[j], acc[i][j]);
    }
  }
  #pragma unroll
  for (int i=0;i<4;i++){
    int j = j0 + ty*4 + i;
    float bias = bg[j];
    int bb = j >> 3, u = j & 7;
    #pragma unroll
    for (int jj=0;jj<4;jj++){
      int t = t0 + tx*4 + jj;
      size_t idx = (((size_t)bb*SEQ + t)*8 + u)*4 + gate;   // [b][t][u][g]
      xproj[idx] = f2bf(acc[i][jj] + bias);
    }
  }
}

// ---------------- Phase B: persistent scan (R1 protocol verbatim) + y epilogue ----------------
// 256 blocks x 512 thr (8 waves). Wave w of block b owns hidden unit u = 8b+w,
// 4 gate h-rows (4x2048 fp32) streamed from cache (NO pin — R6 falsified that).
// Exchange protocol = R1 verbatim (proven 4190 us; R3/R7 poll rewrites both
// regressed >2x — protocol is frozen): fp32 4-byte agent-relaxed publishes;
// each thread polls its own 16 B slice with 2x8B atomic loads, reissuing only
// stale halves; truncate-pack bf16 -> LDS (dbuf by t&1); ONE __syncthreads per
// step; in-wave butterfly + activations; lane 0 publishes immediately.
//
// Only off-protocol changes vs R1:
//  * xp PREFETCH: step t+1's xproj load issues after the barrier (consumed
//    next iter, keep-alive pinned after the dot) — the VMEM queue ahead of
//    the poll loads is empty (R4 lesson: VMEM before polls delays detect).
//  * fused y epilogue (proven in R4/R5/R6), replacing the ygemm launch.
__global__ __launch_bounds__(512, 2)
void lstm_scan(const float* __restrict__ Wf, const float* __restrict__ Wi,
               const float* __restrict__ Wc, const float* __restrict__ Wo,
               const unsigned short* __restrict__ xproj,
               const float* __restrict__ Wy, const float* __restrict__ byv,
               float* __restrict__ hist,      // d_out hidden region [SEQ][HID]
               float* __restrict__ yout)      // d_out y region [SEQ][OUTW]
{
  const int b    = blockIdx.x;
  const int tid  = threadIdx.x;
  const int wv   = tid >> 6;
  const int lane = tid & 63;
  const int u    = b*8 + wv;

  __shared__ unsigned int h_lds[2][HID/2];  // packed bf16 pairs: word W = cols (2W,2W+1)
  __shared__ float As[16][68];              // epilogue staging
  __shared__ float Bs[16][68];

  // fp32 h-weights: wreg[r][kc*8+j] = W_{gate r}[u][8*lane + 512*kc + j]
  const float* const Wm[4] = {Wf, Wi, Wc, Wo};
  float wreg[4][32];
  #pragma unroll
  for (int r=0;r<4;r++){
    const float* rowp = Wm[r] + (size_t)u*3072;
    #pragma unroll
    for (int kc=0;kc<4;kc++){
      float4 f0 = *(const float4*)(rowp + 8*lane + 512*kc);
      float4 f1 = *(const float4*)(rowp + 8*lane + 512*kc + 4);
      wreg[r][kc*8+0]=f0.x; wreg[r][kc*8+1]=f0.y; wreg[r][kc*8+2]=f0.z; wreg[r][kc*8+3]=f0.w;
      wreg[r][kc*8+4]=f1.x; wreg[r][kc*8+5]=f1.y; wreg[r][kc*8+6]=f1.z; wreg[r][kc*8+7]=f1.w;
    }
  }

  float c = 0.0f;
  const unsigned short* xpp = xproj + (size_t)b*SEQ*32 + wv*4 + lane; // lane<4 valid

  // preload xp for t=0 (before the loop; no polls yet to interfere with)
  float xp = (lane < 4) ? bf_lo((unsigned)xpp[0]) : 0.0f;

  for (int t=0; t<SEQ; t++){
    // ---- acquire h_{t-1}: R1 sentinel poll, verbatim; NO VMEM ahead of it ----
    uint2 pk;
    if (t == 0){
      pk.x = 0u; pk.y = 0u;                  // h_{-1} = 0 (bf16 zeros)
    } else {
      const unsigned long long* hp =
        (const unsigned long long*)(hist + (size_t)(t-1)*HID) + 2*tid;  // floats 4tid..4tid+3
      unsigned long long qa = __hip_atomic_load(hp,   __ATOMIC_RELAXED, __HIP_MEMORY_SCOPE_AGENT);
      unsigned long long qb = __hip_atomic_load(hp+1, __ATOMIC_RELAXED, __HIP_MEMORY_SCOPE_AGENT);
      int gd = 0;
      for(;;){
        bool ba = ((unsigned)qa==SENT) | ((unsigned)(qa>>32)==SENT);
        bool bb = ((unsigned)qb==SENT) | ((unsigned)(qb>>32)==SENT);
        if (!(ba|bb) || gd >= (1<<17)) break;   // guard: fail wrong, never hang
        if (ba) qa = __hip_atomic_load(hp,   __ATOMIC_RELAXED, __HIP_MEMORY_SCOPE_AGENT);
        if (bb) qb = __hip_atomic_load(hp+1, __ATOMIC_RELAXED, __HIP_MEMORY_SCOPE_AGENT);
        gd++;
      }
      unsigned a0=(unsigned)qa, a1=(unsigned)(qa>>32), a2=(unsigned)qb, a3=(unsigned)(qb>>32);
      pk.x = (a1 & 0xffff0000u) | (a0 >> 16);   // truncate-pack to bf16 pairs
      pk.y = (a3 & 0xffff0000u) | (a2 >> 16);
    }
    const int p = t & 1;
    *(uint2*)&h_lds[p][2*tid] = pk;
    __syncthreads();                          // the ONLY barrier per step

    // ---- prefetch NEXT step's xp (VMEM queue is poll-free here; hides under dot) ----
    float xp_next = 0.0f;
    if (t+1 < SEQ)
      xp_next = (lane < 4) ? bf_lo((unsigned)xpp[(size_t)(t+1)*32]) : 0.0f;

    // ---- dot: 4 gate rows x 32 cols/lane (R1 verbatim) ----
    float acc[4] = {0.f,0.f,0.f,0.f};
    #pragma unroll
    for (int kc=0;kc<4;kc++){
      uint4 hw = *(const uint4*)&h_lds[p][4*lane + 256*kc];   // cols 8*lane+512*kc+0..7
      float hf[8];
      hf[0]=bf_lo(hw.x); hf[1]=bf_hi(hw.x); hf[2]=bf_lo(hw.y); hf[3]=bf_hi(hw.y);
      hf[4]=bf_lo(hw.z); hf[5]=bf_hi(hw.z); hf[6]=bf_lo(hw.w); hf[7]=bf_hi(hw.w);
      #pragma unroll
      for (int r=0;r<4;r++)
        #pragma unroll
        for (int j=0;j<8;j++)
          acc[r] = fmaf(wreg[r][kc*8+j], hf[j], acc[r]);
    }
    // keep-alive: materialize xp_next here (post-dot), so its load cannot sink
    // past the publish into the next iteration's poll slot
    asm volatile("" : "+v"(xp_next));

    // ---- pair-folding butterfly: lane l ends with gate (l&3) fully reduced ----
    const int b0f = lane & 1;
    const int b1f = lane & 2;
    float x01 = b0f ? acc[1] : acc[0];
    float y01 = b0f ? acc[0] : acc[1];
    x01 += __shfl_xor(y01, 1);
    float x23 = b0f ? acc[3] : acc[2];
    float y23 = b0f ? acc[2] : acc[3];
    x23 += __shfl_xor(y23, 1);
    float xk = b1f ? x23 : x01;
    float yk = b1f ? x01 : x23;
    xk += __shfl_xor(yk, 2);
    xk += __shfl_xor(xk, 4);
    xk += __shfl_xor(xk, 8);
    xk += __shfl_xor(xk, 16);
    xk += __shfl_xor(xk, 32);

    // ---- activations in-wave ----
    float pre = xk + __shfl(xp, lane & 3);
    const bool ist = ((lane & 3) == 2);        // gate 2 = tanh, others sigmoid
    float px = ist ? fminf(15.0f, fmaxf(-15.0f, pre)) : pre;
    float e  = __expf(ist ? -2.0f*px : -px);
    float d  = 1.0f/(1.0f + e);
    float gv = ist ? (1.0f - e)*d : d;

    float f  = __shfl(gv, 0);
    float ii = __shfl(gv, 1);
    float cg = __shfl(gv, 2);
    float o  = __shfl(gv, 3);

    c = fmaf(f, c, ii*cg);
    float cx = fminf(15.0f, fmaxf(-15.0f, c));
    float e2 = __expf(-2.0f*cx);
    float h  = o * (1.0f - e2)/(1.0f + e2);

    // ---- publish immediately (fire-and-forget, self-validating) ----
    if (lane == 0)
      __hip_atomic_store(hist + (size_t)t*HID + u, h,
                         __ATOMIC_RELAXED, __HIP_MEMORY_SCOPE_AGENT);

    xp = xp_next;
  }

  // ================= epilogue: y[t][o] = W_y[o] @ h_t + b_y[o] =================
  // Row SEQ-1 complete => all rows complete (h_t required full h_{t-1}).
  {
    const unsigned long long* hp =
      (const unsigned long long*)(hist + (size_t)(SEQ-1)*HID) + 2*tid;
    unsigned long long qa = __hip_atomic_load(hp,   __ATOMIC_RELAXED, __HIP_MEMORY_SCOPE_AGENT);
    unsigned long long qb = __hip_atomic_load(hp+1, __ATOMIC_RELAXED, __HIP_MEMORY_SCOPE_AGENT);
    int gd = 0;
    for(;;){
      bool ba = ((unsigned)qa==SENT) | ((unsigned)(qa>>32)==SENT);
      bool bb = ((unsigned)qb==SENT) | ((unsigned)(qb>>32)==SENT);
      if (!(ba|bb) || gd >= (1<<17)) break;
      if (ba) qa = __hip_atomic_load(hp,   __ATOMIC_RELAXED, __HIP_MEMORY_SCOPE_AGENT);
      if (bb) qb = __hip_atomic_load(hp+1, __ATOMIC_RELAXED, __HIP_MEMORY_SCOPE_AGENT);
      gd++;
    }
  }
  __syncthreads();

  // one 64x64 tile per block; tid<256 computes (proven ygemm body), barriers uniform
  const int t0 = (b >> 3) * 64;
  const int o0 = (b & 7) * 64;
  const int tx = tid & 15, ty = (tid >> 4) & 15;
  const int lr = (tid & 255) >> 2;
  const int lk = (tid & 3) * 4;
  float yacc[4][4] = {};
  for (int k0 = 0; k0 < HID; k0 += 16){
    if (tid < 256){
      float4 av = *(const float4*)(hist + (size_t)(t0+lr)*HID + k0 + lk);
      float4 bv = *(const float4*)(Wy   + (size_t)(o0+lr)*HID + k0 + lk);
      As[lk+0][lr]=av.x; As[lk+1][lr]=av.y; As[lk+2][lr]=av.z; As[lk+3][lr]=av.w;
      Bs[lk+0][lr]=bv.x; Bs[lk+1][lr]=bv.y; Bs[lk+2][lr]=bv.z; Bs[lk+3][lr]=bv.w;
    }
    __syncthreads();
    if (tid < 256){
      #pragma unroll
      for (int kk=0;kk<16;kk++){
        float a[4], bb2[4];
        #pragma unroll
        for (int i=0;i<4;i++) a[i]   = As[kk][ty*4+i];
        #pragma unroll
        for (int j=0;j<4;j++) bb2[j] = Bs[kk][tx*4+j];
        #pragma unroll
        for (int i=0;i<4;i++)
          #pragma unroll
          for (int j=0;j<4;j++)
            yacc[i][j] = fmaf(a[i], bb2[j], yacc[i][j]);
      }
    }
    __syncthreads();
  }
  if (tid < 256){
    #pragma unroll
    for (int i=0;i<4;i++){
      int t = t0 + ty*4 + i;
      #pragma unroll
      for (int jj=0;jj<4;jj++){
        int o = o0 + tx*4 + jj;
        yout[(size_t)t*OUTW + o] = yacc[i][jj] + byv[o];
      }
    }
  }
}

extern "C" void kernel_launch(void* const* d_in, const int* in_sizes, int n_in,
                              void* d_out, int out_size, void* d_ws, size_t ws_size,
                              hipStream_t stream) {
  const float* X  = (const float*)d_in[0];
  const float* Wf = (const float*)d_in[1];
  const float* bf = (const float*)d_in[2];
  const float* Wi = (const float*)d_in[3];
  const float* bi = (const float*)d_in[4];
  const float* Wc = (const float*)d_in[5];
  const float* bc = (const float*)d_in[6];
  const float* Wo = (const float*)d_in[7];
  const float* bo = (const float*)d_in[8];
  const float* Wy = (const float*)d_in[9];
  const float* by = (const float*)d_in[10];

  float* yout = (float*)d_out;                       // [2048][512]
  float* hist = (float*)d_out + (size_t)SEQ*OUTW;    // [2048][2048]

  const size_t XPROJ_BYTES = (size_t)256*SEQ*32*sizeof(unsigned short); // 33,554,432
  if (ws_size < XPROJ_BYTES) return;   // clean failure instead of corruption

  unsigned short* xproj = (unsigned short*)d_ws;

  // sentinel-fill hist (16 MB); stream-ordered before the scan
  fill_hist<<<(SEQ*(size_t)HID/4)/256, 256, 0, stream>>>((uint4*)hist);

  dim3 gA(32, 128);
  xproj_gemm<<<gA, 256, 0, stream>>>(Wf,Wi,Wc,Wo, bf,bi,bc,bo, X, xproj);
  lstm_scan<<<256, 512, 0, stream>>>(Wf,Wi,Wc,Wo, xproj, Wy, by, hist, yout);
}

// Round 9
// 4837.765 us; speedup vs baseline: 2.9135x; 2.9135x over previous
//
#include <hip/hip_runtime.h>
#include <stdint.h>

#define SEQ  2048
#define HID  2048
#define INP  1024
#define OUTW 512
#define SENT 0x7F7F7F7Fu   // 3.39e38f; |h|<1 so a real h word never matches

__device__ __forceinline__ unsigned short f2bf(float x){
  unsigned int u = __float_as_uint(x);
  u += 0x7fffu + ((u >> 16) & 1u);           // RNE
  return (unsigned short)(u >> 16);
}
__device__ __forceinline__ float bf_lo(unsigned int w){ return __uint_as_float(w << 16); }
__device__ __forceinline__ float bf_hi(unsigned int w){ return __uint_as_float(w & 0xffff0000u); }

// ---------------- Phase 0: sentinel-fill hist (R1 verbatim) ----------------
__global__ __launch_bounds__(256)
void fill_hist(uint4* __restrict__ hist4){
  size_t i = (size_t)blockIdx.x*blockDim.x + threadIdx.x;   // 1,048,576 uint4 = 16 MB
  hist4[i] = make_uint4(SENT,SENT,SENT,SENT);
}

// ---------------- Phase A: Xproj[b][t][u][g], 128x128 tile / 8x8 micro-tile ----------------
// C[r0+row][t] = W_gate[j][2048:] @ X[t] + b; same output layout as R1
// ([b][t][u][g] ushort bf16). 256 thr, 8x8 accum/thread, K-step 16, LDS-staged.
// Each 128-row tile lies entirely within one gate (2048 % 128 == 0).
__global__ __launch_bounds__(256)
void xproj_gemm(const float* __restrict__ Wf, const float* __restrict__ Wi,
                const float* __restrict__ Wc, const float* __restrict__ Wo,
                const float* __restrict__ bfv, const float* __restrict__ biv,
                const float* __restrict__ bcv, const float* __restrict__ bov,
                const float* __restrict__ X, unsigned short* __restrict__ xproj)
{
  __shared__ float As[16][132];   // [k][row], +4 pad
  __shared__ float Bs[16][132];   // [k][t]
  const int t0 = blockIdx.x * 128;
  const int r0 = blockIdx.y * 128;
  const int gate = r0 >> 11;
  const int j0 = r0 & 2047;
  const float* Wg = gate==0?Wf:gate==1?Wi:gate==2?Wc:Wo;
  const float* bg = gate==0?bfv:gate==1?biv:gate==2?bcv:bov;
  const int tid = threadIdx.x;
  const int tx = tid & 15;             // output col group: t = t0 + tx*8 + jj
  const int ty = tid >> 4;             // output row group: j = j0 + ty*8 + i
  const int lr = tid >> 1;             // stage row 0..127
  const int lk = (tid & 1) * 8;        // stage k offset 0 or 8
  float acc[8][8] = {};
  for (int k0 = 0; k0 < INP; k0 += 16){
    float4 a0 = *(const float4*)(Wg + (size_t)(j0+lr)*3072 + 2048 + k0 + lk);
    float4 a1 = *(const float4*)(Wg + (size_t)(j0+lr)*3072 + 2048 + k0 + lk + 4);
    float4 b0 = *(const float4*)(X  + (size_t)(t0+lr)*INP  + k0 + lk);
    float4 b1 = *(const float4*)(X  + (size_t)(t0+lr)*INP  + k0 + lk + 4);
    __syncthreads();
    As[lk+0][lr]=a0.x; As[lk+1][lr]=a0.y; As[lk+2][lr]=a0.z; As[lk+3][lr]=a0.w;
    As[lk+4][lr]=a1.x; As[lk+5][lr]=a1.y; As[lk+6][lr]=a1.z; As[lk+7][lr]=a1.w;
    Bs[lk+0][lr]=b0.x; Bs[lk+1][lr]=b0.y; Bs[lk+2][lr]=b0.z; Bs[lk+3][lr]=b0.w;
    Bs[lk+4][lr]=b1.x; Bs[lk+5][lr]=b1.y; Bs[lk+6][lr]=b1.z; Bs[lk+7][lr]=b1.w;
    __syncthreads();
    #pragma unroll
    for (int kk=0;kk<16;kk++){
      float a[8], bb[8];
      #pragma unroll
      for (int i=0;i<8;i++) a[i]  = As[kk][ty*8+i];
      #pragma unroll
      for (int j=0;j<8;j++) bb[j] = Bs[kk][tx*8+j];
      #pragma unroll
      for (int i=0;i<8;i++)
        #pragma unroll
        for (int j=0;j<8;j++)
          acc[i][j] = fmaf(a[i], bb[j], acc[i][j]);
    }
  }
  #pragma unroll
  for (int i=0;i<8;i++){
    int j = j0 + ty*8 + i;
    float bias = bg[j];
    int bb = j >> 3, u = j & 7;
    #pragma unroll
    for (int jj=0;jj<8;jj++){
      int t = t0 + tx*8 + jj;
      size_t idx = (((size_t)bb*SEQ + t)*8 + u)*4 + gate;   // [b][t][u][g]
      xproj[idx] = f2bf(acc[i][jj] + bias);
    }
  }
}

// ---------------- Phase B: persistent recurrent scan, barrier-free (R1 VERBATIM) ----------------
// FROZEN. R1 measured 4190 us. Every modification attempt (R3 reg-direct poll,
// R6 weight pin, R7 two-stream poll, R8 xp prefetch) tipped a codegen cliff:
// the compiler stops holding the 128 weight floats resident and re-streams
// them per step (FETCH 116->500-620 MB, VALUBusy ->14%, dur 3x). Do not edit.
__global__ __launch_bounds__(512, 2)
void lstm_persistent(const float* __restrict__ Wf, const float* __restrict__ Wi,
                     const float* __restrict__ Wc, const float* __restrict__ Wo,
                     const unsigned short* __restrict__ xproj,
                     float* __restrict__ hist)          // d_out hidden region [SEQ][HID]
{
  const int b    = blockIdx.x;
  const int tid  = threadIdx.x;
  const int wv   = tid >> 6;
  const int lane = tid & 63;
  const int u    = b*8 + wv;                 // this wave's hidden unit

  __shared__ unsigned int h_lds[2][HID/2];   // packed bf16 pairs: word W = cols (2W,2W+1)

  // fp32 weights: wreg[r][kc*8+j] = W_{gate r}[u][8*lane + 512*kc + j]
  const float* const Wm[4] = {Wf, Wi, Wc, Wo};
  float wreg[4][32];
  #pragma unroll
  for (int r=0;r<4;r++){
    const float* rowp = Wm[r] + (size_t)u*3072;
    #pragma unroll
    for (int kc=0;kc<4;kc++){
      float4 f0 = *(const float4*)(rowp + 8*lane + 512*kc);
      float4 f1 = *(const float4*)(rowp + 8*lane + 512*kc + 4);
      wreg[r][kc*8+0]=f0.x; wreg[r][kc*8+1]=f0.y; wreg[r][kc*8+2]=f0.z; wreg[r][kc*8+3]=f0.w;
      wreg[r][kc*8+4]=f1.x; wreg[r][kc*8+5]=f1.y; wreg[r][kc*8+6]=f1.z; wreg[r][kc*8+7]=f1.w;
    }
  }

  float c = 0.0f;                            // cell state, redundant across lanes
  const unsigned short* xpp = xproj + (size_t)b*SEQ*32 + wv*4 + lane; // valid lane<4

  for (int t=0; t<SEQ; t++){
    // x-projection (tiny, cached) — issue before the h spin
    float xp = (lane < 4) ? bf_lo((unsigned)xpp[(size_t)t*32]) : 0.0f;

    // ---- acquire h_{t-1}: self-validating sentinel poll, LLC-scope loads ----
    uint2 pk;
    if (t == 0){
      pk.x = 0u; pk.y = 0u;                  // h_{-1} = 0 (bf16 zeros)
    } else {
      const unsigned long long* hp =
        (const unsigned long long*)(hist + (size_t)(t-1)*HID) + 2*tid;  // floats 4tid..4tid+3
      unsigned long long qa = __hip_atomic_load(hp,   __ATOMIC_RELAXED, __HIP_MEMORY_SCOPE_AGENT);
      unsigned long long qb = __hip_atomic_load(hp+1, __ATOMIC_RELAXED, __HIP_MEMORY_SCOPE_AGENT);
      int gd = 0;
      for(;;){
        bool ba = ((unsigned)qa==SENT) | ((unsigned)(qa>>32)==SENT);
        bool bb = ((unsigned)qb==SENT) | ((unsigned)(qb>>32)==SENT);
        if (!(ba|bb) || gd >= (1<<17)) break;   // guard: fail wrong, never hang
        if (ba) qa = __hip_atomic_load(hp,   __ATOMIC_RELAXED, __HIP_MEMORY_SCOPE_AGENT);
        if (bb) qb = __hip_atomic_load(hp+1, __ATOMIC_RELAXED, __HIP_MEMORY_SCOPE_AGENT);
        gd++;
      }
      unsigned a0=(unsigned)qa, a1=(unsigned)(qa>>32), a2=(unsigned)qb, a3=(unsigned)(qb>>32);
      pk.x = (a1 & 0xffff0000u) | (a0 >> 16);   // truncate-pack to bf16 pairs
      pk.y = (a3 & 0xffff0000u) | (a2 >> 16);
    }
    const int p = t & 1;
    *(uint2*)&h_lds[p][2*tid] = pk;
    __syncthreads();                          // the ONLY barrier per step

    // ---- dot: 4 gate rows x 32 cols/lane against register-resident weights ----
    float acc[4] = {0.f,0.f,0.f,0.f};
    #pragma unroll
    for (int kc=0;kc<4;kc++){
      uint4 hw = *(const uint4*)&h_lds[p][4*lane + 256*kc];   // cols 8*lane+512*kc+0..7
      float hf[8];
      hf[0]=bf_lo(hw.x); hf[1]=bf_hi(hw.x); hf[2]=bf_lo(hw.y); hf[3]=bf_hi(hw.y);
      hf[4]=bf_lo(hw.z); hf[5]=bf_hi(hw.z); hf[6]=bf_lo(hw.w); hf[7]=bf_hi(hw.w);
      #pragma unroll
      for (int r=0;r<4;r++)
        #pragma unroll
        for (int j=0;j<8;j++)
          acc[r] = fmaf(wreg[r][kc*8+j], hf[j], acc[r]);
    }

    // ---- pair-folding butterfly: lane l ends with gate (l&3) fully reduced ----
    const int b0 = lane & 1;
    const int b1 = lane & 2;
    float x01 = b0 ? acc[1] : acc[0];
    float y01 = b0 ? acc[0] : acc[1];
    x01 += __shfl_xor(y01, 1);                // even: gate0 pair-sum, odd: gate1
    float x23 = b0 ? acc[3] : acc[2];
    float y23 = b0 ? acc[2] : acc[3];
    x23 += __shfl_xor(y23, 1);                // even: gate2 pair-sum, odd: gate3
    float xk = b1 ? x23 : x01;
    float yk = b1 ? x01 : x23;
    xk += __shfl_xor(yk, 2);                  // lane (l&3)=r holds gate r over quad
    xk += __shfl_xor(xk, 4);
    xk += __shfl_xor(xk, 8);
    xk += __shfl_xor(xk, 16);
    xk += __shfl_xor(xk, 32);                 // full 64-lane sum of gate (l&3)

    // ---- activations in-wave (no divergence: shared exp + rcp form) ----
    float pre = xk + __shfl(xp, lane & 3);    // add this gate's x-projection
    const bool ist = ((lane & 3) == 2);       // gate 2 = tanh, others sigmoid
    float px = ist ? fminf(15.0f, fmaxf(-15.0f, pre)) : pre;
    float e  = __expf(ist ? -2.0f*px : -px);
    float d  = 1.0f/(1.0f + e);
    float gv = ist ? (1.0f - e)*d : d;        // tanh=(1-e)/(1+e), sigmoid=1/(1+e)

    float f  = __shfl(gv, 0);
    float ii = __shfl(gv, 1);
    float cg = __shfl(gv, 2);
    float o  = __shfl(gv, 3);

    c = fmaf(f, c, ii*cg);
    float cx = fminf(15.0f, fmaxf(-15.0f, c));
    float e2 = __expf(-2.0f*cx);
    float h  = o * (1.0f - e2)/(1.0f + e2);

    // ---- publish immediately (fire-and-forget, self-validating) ----
    if (lane == 0)
      __hip_atomic_store(hist + (size_t)t*HID + u, h,
                         __ATOMIC_RELAXED, __HIP_MEMORY_SCOPE_AGENT);
  }
}

// ---------------- Phase C: y[t][o] = W_y[o] @ h_t + b_y[o] (R1 verbatim) ----------------
__global__ __launch_bounds__(256)
void ygemm(const float* __restrict__ hist, const float* __restrict__ Wy,
           const float* __restrict__ by, float* __restrict__ yout)
{
  __shared__ float As[16][68];
  __shared__ float Bs[16][68];
  const int o0 = blockIdx.x * 64;
  const int t0 = blockIdx.y * 64;
  const int tid = threadIdx.x;
  const int tx = tid & 15, ty = tid >> 4;
  const int lr = tid >> 2;
  const int lk = (tid & 3) * 4;
  float acc[4][4] = {};
  for (int k0 = 0; k0 < HID; k0 += 16){
    float4 av = *(const float4*)(hist + (size_t)(t0+lr)*HID + k0 + lk);
    float4 bv = *(const float4*)(Wy   + (size_t)(o0+lr)*HID + k0 + lk);
    __syncthreads();
    As[lk+0][lr]=av.x; As[lk+1][lr]=av.y; As[lk+2][lr]=av.z; As[lk+3][lr]=av.w;
    Bs[lk+0][lr]=bv.x; Bs[lk+1][lr]=bv.y; Bs[lk+2][lr]=bv.z; Bs[lk+3][lr]=bv.w;
    __syncthreads();
    #pragma unroll
    for (int kk=0;kk<16;kk++){
      float a[4], bb[4];
      #pragma unroll
      for (int i=0;i<4;i++) a[i]  = As[kk][ty*4+i];
      #pragma unroll
      for (int j=0;j<4;j++) bb[j] = Bs[kk][tx*4+j];
      #pragma unroll
      for (int i=0;i<4;i++)
        #pragma unroll
        for (int j=0;j<4;j++)
          acc[i][j] = fmaf(a[i], bb[j], acc[i][j]);
    }
  }
  #pragma unroll
  for (int i=0;i<4;i++){
    int t = t0 + ty*4 + i;
    #pragma unroll
    for (int jj=0;jj<4;jj++){
      int o = o0 + tx*4 + jj;
      yout[(size_t)t*OUTW + o] = acc[i][jj] + by[o];
    }
  }
}

extern "C" void kernel_launch(void* const* d_in, const int* in_sizes, int n_in,
                              void* d_out, int out_size, void* d_ws, size_t ws_size,
                              hipStream_t stream) {
  const float* X  = (const float*)d_in[0];
  const float* Wf = (const float*)d_in[1];
  const float* bf = (const float*)d_in[2];
  const float* Wi = (const float*)d_in[3];
  const float* bi = (const float*)d_in[4];
  const float* Wc = (const float*)d_in[5];
  const float* bc = (const float*)d_in[6];
  const float* Wo = (const float*)d_in[7];
  const float* bo = (const float*)d_in[8];
  const float* Wy = (const float*)d_in[9];
  const float* by = (const float*)d_in[10];

  float* yout = (float*)d_out;                       // [2048][512]
  float* hist = (float*)d_out + (size_t)SEQ*OUTW;    // [2048][2048]

  const size_t XPROJ_BYTES = (size_t)256*SEQ*32*sizeof(unsigned short); // 33,554,432
  if (ws_size < XPROJ_BYTES) return;   // clean failure instead of corruption

  unsigned short* xproj = (unsigned short*)d_ws;

  // sentinel-fill hist (16 MB); stream-ordered before the scan
  fill_hist<<<(SEQ*(size_t)HID/4)/256, 256, 0, stream>>>((uint4*)hist);

  dim3 gA(16, 64);   // 128x128 tiles: 2048/128 x 8192/128
  xproj_gemm<<<gA, 256, 0, stream>>>(Wf,Wi,Wc,Wo, bf,bi,bc,bo, X, xproj);
  lstm_persistent<<<256, 512, 0, stream>>>(Wf,Wi,Wc,Wo, xproj, hist);
  dim3 gY(8, 32);
  ygemm<<<gY, 256, 0, stream>>>(hist, Wy, by, yout);
}